// Round 6
// baseline (37.401 us; speedup 1.0000x reference)
//
#include <hip/hip_runtime.h>

// SoftPattern: score = sum_{t=4}^{T-1} prod_{p=0}^{4} sigmoid(e_{doc[t-4+p]} . W[:,p] + b[p])
// W = diags[1]; only pattern positions 0..4 contribute.
//
// K1: fused projection+combine+sigmoid -> sig[v][8]
//     block=384: 6 d-groups (50 rows) x 64 lanes; VBLK=128 (512B-aligned wave segs).
//     wl padded to stride 8 -> ds_read_b128+b32 merge (2 LDS instr/d instead of 5).
//     Block 0 also resets K2's ticket counter.
// K2: windowed 5-term products, LDS-staged token rows, 1024-thread blocks,
//     deterministic last-block final reduction (threadfence + atomic ticket).

#define WORD_DIM 300
#define VOCAB    50000
#define PLEN     6
#define DOC_LEN  500000

#define GROUPS   6
#define DCHUNK   50                    // WORD_DIM / GROUPS
#define K1_BLOCK (GROUPS * 64)         // 384
#define VBLK     128                   // 64 lanes x float2

// ------------- K1: sig[v][p] = sigmoid(sum_d E[d][v]*W[d][p] + b[p]) -------------
__global__ __launch_bounds__(K1_BLOCK) void proj_sig_fused(
    const float* __restrict__ emb,     // (WORD_DIM, VOCAB)
    const float* __restrict__ diags,   // (3, WORD_DIM, PLEN)
    const float* __restrict__ bias,    // (3, PLEN)
    float* __restrict__ sig,           // (VOCAB, 8) rows, cols 0..4 valid
    unsigned int* __restrict__ ctr)    // K2 ticket (reset here, visible at K1 completion)
{
    __shared__ float wl[WORD_DIM * 8];                   // 9.6 KB, stride-8: 16B-aligned rows
    __shared__ float part[GROUPS - 1][64][11];           // 13.75 KB, stride-11: 2-way max
    const int tid = threadIdx.x;
    if (blockIdx.x == 0 && tid == 0) *ctr = 0u;
    for (int i = tid; i < WORD_DIM * 5; i += K1_BLOCK) {
        int d = i / 5, p = i % 5;
        wl[d * 8 + p] = diags[WORD_DIM * PLEN + d * PLEN + p];   // diags[1][d][p]
    }
    __syncthreads();

    const int g   = tid >> 6;          // d-group == wave index
    const int u   = tid & 63;          // lane
    const int v2  = blockIdx.x * VBLK + u * 2;
    const bool act = (v2 < VOCAB);     // last block: 40 active lanes
    const int d0  = g * DCHUNK;

    float a[10] = {0.f, 0.f, 0.f, 0.f, 0.f, 0.f, 0.f, 0.f, 0.f, 0.f};
    if (act) {
        const float* __restrict__ col = emb + (size_t)d0 * VOCAB + v2;
        #pragma unroll 10
        for (int dd = 0; dd < DCHUNK; ++dd) {
            float2 x = *reinterpret_cast<const float2*>(&col[(size_t)dd * VOCAB]);
            const float* w = &wl[(d0 + dd) * 8];         // 32B-aligned -> b128+b32 merge
            a[0] += x.x * w[0]; a[1] += x.x * w[1]; a[2] += x.x * w[2];
            a[3] += x.x * w[3]; a[4] += x.x * w[4];
            a[5] += x.y * w[0]; a[6] += x.y * w[1]; a[7] += x.y * w[2];
            a[8] += x.y * w[3]; a[9] += x.y * w[4];
        }
    }
    if (g > 0 && act) {
        #pragma unroll
        for (int k = 0; k < 10; ++k) part[g - 1][u][k] = a[k];
    }
    __syncthreads();
    if (g == 0 && act) {
        #pragma unroll
        for (int k = 0; k < 10; ++k) {
            float s = a[k];
            #pragma unroll
            for (int q = 0; q < GROUPS - 1; ++q) s += part[q][u][k];
            a[k] = s;
        }
        float* r0 = &sig[(size_t)v2 * 8];
        float* r1 = &sig[(size_t)(v2 + 1) * 8];
        #pragma unroll
        for (int p = 0; p < 5; ++p) {
            float b = bias[PLEN + p];                    // bias[1][p]
            r0[p] = 1.f / (1.f + __expf(-(a[p]     + b)));
            r1[p] = 1.f / (1.f + __expf(-(a[5 + p] + b)));
        }
    }
}

// ------------- K2: windowed products + last-block deterministic reduce -------------
#define K2_BLOCK 1024
#define K2_TOK   (K2_BLOCK + 4)
#define K2_GRID  ((DOC_LEN - 4 + K2_BLOCK - 1) / K2_BLOCK)   // 489

__global__ __launch_bounds__(K2_BLOCK) void score_kernel(
    const int* __restrict__ doc,
    const float* __restrict__ sig,     // (VOCAB, 8)
    float* __restrict__ partials,      // (K2_GRID,)
    unsigned int* __restrict__ ctr,
    float* __restrict__ out)
{
    __shared__ float srow[5][K2_TOK];  // plane-per-position: conflict-free stride-1
    const int tid  = threadIdx.x;
    const int base = blockIdx.x * K2_BLOCK + 4;          // first window end t
    for (int i = tid; i < K2_TOK; i += K2_BLOCK) {
        int tok_t = base - 4 + i;
        if (tok_t < DOC_LEN) {
            const float* row = &sig[(size_t)doc[tok_t] * 8];
            float4 r4 = *reinterpret_cast<const float4*>(row);
            srow[0][i] = r4.x; srow[1][i] = r4.y; srow[2][i] = r4.z; srow[3][i] = r4.w;
            srow[4][i] = row[4];
        }
    }
    __syncthreads();

    const int t = base + tid;
    float prod = 0.f;
    if (t < DOC_LEN) {
        prod = srow[0][tid] * srow[1][tid + 1] * srow[2][tid + 2]
             * srow[3][tid + 3] * srow[4][tid + 4];
    }
    #pragma unroll
    for (int off = 32; off > 0; off >>= 1)
        prod += __shfl_down(prod, off, 64);
    __shared__ float wsum[K2_BLOCK / 64];
    const int lane = tid & 63;
    const int wid  = tid >> 6;
    if (lane == 0) wsum[wid] = prod;
    __syncthreads();

    __shared__ bool is_last;
    if (tid == 0) {
        float s = 0.f;
        #pragma unroll
        for (int w = 0; w < K2_BLOCK / 64; ++w) s += wsum[w];
        partials[blockIdx.x] = s;
        __threadfence();                                  // publish partial (device scope)
        unsigned int old = atomicAdd(ctr, 1u);            // device-scope by default
        is_last = (old == K2_GRID - 1);
    }
    __syncthreads();
    if (!is_last) return;

    // last block: deterministic final sum over fixed-order partials
    __threadfence();                                      // acquire all partials
    float s = (tid < K2_GRID) ? partials[tid] : 0.f;
    #pragma unroll
    for (int off = 32; off > 0; off >>= 1)
        s += __shfl_down(s, off, 64);
    if (lane == 0) wsum[wid] = s;
    __syncthreads();
    if (tid == 0) {
        float tot = 0.f;
        #pragma unroll
        for (int w = 0; w < K2_BLOCK / 64; ++w) tot += wsum[w];
        out[0] = tot;
    }
}

extern "C" void kernel_launch(void* const* d_in, const int* in_sizes, int n_in,
                              void* d_out, int out_size, void* d_ws, size_t ws_size,
                              hipStream_t stream) {
    const float* emb   = (const float*)d_in[0];   // (300, 50000)
    const float* diags = (const float*)d_in[1];   // (3, 300, 6)
    const float* bias  = (const float*)d_in[2];   // (3, 6)
    const int*   doc   = (const int*)d_in[3];     // (500000,)
    float* out = (float*)d_out;

    float* ws = (float*)d_ws;
    float* sig   = ws;                            // VOCAB*8 floats = 1.6 MB
    float* bpart = sig + (size_t)VOCAB * 8;       // K2_GRID block partials
    unsigned int* ctr = (unsigned int*)(bpart + K2_GRID);

    const int blocks1 = (VOCAB + VBLK - 1) / VBLK;                   // 391

    proj_sig_fused<<<blocks1, K1_BLOCK, 0, stream>>>(emb, diags, bias, sig, ctr);
    score_kernel<<<K2_GRID, K2_BLOCK, 0, stream>>>(doc, sig, bpart, ctr, out);
}

// Round 7
// 28.526 us; speedup vs baseline: 1.3111x; 1.3111x over previous
//
#include <hip/hip_runtime.h>

// SoftPattern: score = sum_{t=4}^{T-1} prod_{p=0}^{4} sigmoid(e_{doc[t-4+p]} . W[:,p] + b[p])
// W = diags[1]; only pattern positions 0..4 contribute.
//
// Structure = R5 (3 kernels, no atomic ticket; ticket measured +12us in R4/R6).
// K1 changes only: wl stride 8 (LDS b128 merge), float4 emb loads (VBLK=256).
//
// K1: fused projection+combine+sigmoid -> sig[v][8]
//     block=384: 6 d-groups (50 rows) x 64 lanes; VBLK=256 cols (64 lanes x float4,
//     1024B-aligned wave segments); grid=196 (CU coverage proven non-binding R3->R5).
// K2: windowed 5-term products, LDS-staged token rows, 1024-thread blocks
// K3: final deterministic reduction

#define WORD_DIM 300
#define VOCAB    50000
#define PLEN     6
#define DOC_LEN  500000

#define GROUPS   6
#define DCHUNK   50                    // WORD_DIM / GROUPS
#define K1_BLOCK (GROUPS * 64)         // 384
#define VBLK     256                   // 64 lanes x float4

// ------------- K1: sig[v][p] = sigmoid(sum_d E[d][v]*W[d][p] + b[p]) -------------
__global__ __launch_bounds__(K1_BLOCK) void proj_sig_fused(
    const float* __restrict__ emb,     // (WORD_DIM, VOCAB)
    const float* __restrict__ diags,   // (3, WORD_DIM, PLEN)
    const float* __restrict__ bias,    // (3, PLEN)
    float* __restrict__ sig)           // (VOCAB, 8) rows, cols 0..4 valid
{
    __shared__ float wl[WORD_DIM * 8];                   // 9.6 KB, 32B rows -> b128 merge
    __shared__ float part[GROUPS - 1][64][21];           // 26.9 KB, odd stride: conflict-free
    const int tid = threadIdx.x;
    for (int i = tid; i < WORD_DIM * 5; i += K1_BLOCK) {
        int d = i / 5, p = i % 5;
        wl[d * 8 + p] = diags[WORD_DIM * PLEN + d * PLEN + p];   // diags[1][d][p]
    }
    __syncthreads();

    const int g   = tid >> 6;          // d-group == wave index
    const int u   = tid & 63;          // lane
    const int v4  = blockIdx.x * VBLK + u * 4;
    const bool act = (v4 < VOCAB);     // VOCAB%4==0 -> whole float4 in bounds
    const int d0  = g * DCHUNK;

    float a[20];
    #pragma unroll
    for (int k = 0; k < 20; ++k) a[k] = 0.f;

    if (act) {
        const float* __restrict__ col = emb + (size_t)d0 * VOCAB + v4;
        #pragma unroll 10
        for (int dd = 0; dd < DCHUNK; ++dd) {
            float4 x = *reinterpret_cast<const float4*>(&col[(size_t)dd * VOCAB]);
            const float* w = &wl[(d0 + dd) * 8];         // 32B-aligned -> b128+b32
            #pragma unroll
            for (int p = 0; p < 5; ++p) {
                float wp = w[p];
                a[p]      += x.x * wp;
                a[5 + p]  += x.y * wp;
                a[10 + p] += x.z * wp;
                a[15 + p] += x.w * wp;
            }
        }
    }
    if (g > 0 && act) {
        #pragma unroll
        for (int k = 0; k < 20; ++k) part[g - 1][u][k] = a[k];
    }
    __syncthreads();
    if (g == 0 && act) {
        #pragma unroll
        for (int k = 0; k < 20; ++k) {
            float s = a[k];
            #pragma unroll
            for (int q = 0; q < GROUPS - 1; ++q) s += part[q][u][k];
            a[k] = s;
        }
        #pragma unroll
        for (int j = 0; j < 4; ++j) {
            float* r = &sig[(size_t)(v4 + j) * 8];
            #pragma unroll
            for (int p = 0; p < 5; ++p) {
                float b = bias[PLEN + p];                // bias[1][p]
                r[p] = 1.f / (1.f + __expf(-(a[5 * j + p] + b)));
            }
        }
    }
}

// ------------- K2: windowed products, LDS-staged rows -------------
#define K2_BLOCK 1024
#define K2_TOK   (K2_BLOCK + 4)

__global__ __launch_bounds__(K2_BLOCK) void score_kernel(
    const int* __restrict__ doc,
    const float* __restrict__ sig,     // (VOCAB, 8)
    float* __restrict__ partials)
{
    __shared__ float srow[5][K2_TOK];  // plane-per-position: conflict-free stride-1
    const int tid  = threadIdx.x;
    const int base = blockIdx.x * K2_BLOCK + 4;          // first window end t
    for (int i = tid; i < K2_TOK; i += K2_BLOCK) {
        int tok_t = base - 4 + i;
        if (tok_t < DOC_LEN) {
            const float* row = &sig[(size_t)doc[tok_t] * 8];
            float4 r4 = *reinterpret_cast<const float4*>(row);
            srow[0][i] = r4.x; srow[1][i] = r4.y; srow[2][i] = r4.z; srow[3][i] = r4.w;
            srow[4][i] = row[4];
        }
    }
    __syncthreads();

    const int t = base + tid;
    float prod = 0.f;
    if (t < DOC_LEN) {
        prod = srow[0][tid] * srow[1][tid + 1] * srow[2][tid + 2]
             * srow[3][tid + 3] * srow[4][tid + 4];
    }
    #pragma unroll
    for (int off = 32; off > 0; off >>= 1)
        prod += __shfl_down(prod, off, 64);
    __shared__ float wsum[K2_BLOCK / 64];
    const int lane = tid & 63;
    const int wid  = tid >> 6;
    if (lane == 0) wsum[wid] = prod;
    __syncthreads();
    if (tid == 0) {
        float s = 0.f;
        #pragma unroll
        for (int w = 0; w < K2_BLOCK / 64; ++w) s += wsum[w];
        partials[blockIdx.x] = s;
    }
}

// ------------- K3: final reduction -------------
__global__ __launch_bounds__(512) void reduce_kernel(
    const float* __restrict__ partials, int n, float* __restrict__ out)
{
    float s = 0.f;
    for (int i = threadIdx.x; i < n; i += 512) s += partials[i];
    #pragma unroll
    for (int off = 32; off > 0; off >>= 1)
        s += __shfl_down(s, off, 64);
    __shared__ float wsum[8];
    const int lane = threadIdx.x & 63;
    const int wid  = threadIdx.x >> 6;
    if (lane == 0) wsum[wid] = s;
    __syncthreads();
    if (threadIdx.x == 0) {
        float t = 0.f;
        #pragma unroll
        for (int w = 0; w < 8; ++w) t += wsum[w];
        out[0] = t;
    }
}

extern "C" void kernel_launch(void* const* d_in, const int* in_sizes, int n_in,
                              void* d_out, int out_size, void* d_ws, size_t ws_size,
                              hipStream_t stream) {
    const float* emb   = (const float*)d_in[0];   // (300, 50000)
    const float* diags = (const float*)d_in[1];   // (3, 300, 6)
    const float* bias  = (const float*)d_in[2];   // (3, 6)
    const int*   doc   = (const int*)d_in[3];     // (500000,)
    float* out = (float*)d_out;

    float* ws = (float*)d_ws;
    float* sig   = ws;                            // VOCAB*8 floats = 1.6 MB
    float* bpart = sig + (size_t)VOCAB * 8;       // block partials

    const int blocks1 = (VOCAB + VBLK - 1) / VBLK;                   // 196
    const int nwin    = DOC_LEN - 4;                                 // 499996
    const int blocks2 = (nwin + K2_BLOCK - 1) / K2_BLOCK;            // 489

    proj_sig_fused<<<blocks1, K1_BLOCK, 0, stream>>>(emb, diags, bias, sig);
    score_kernel<<<blocks2, K2_BLOCK, 0, stream>>>(doc, sig, bpart);
    reduce_kernel<<<1, 512, 0, stream>>>(bpart, blocks2, out);
}

// Round 8
// 25.755 us; speedup vs baseline: 1.4522x; 1.1076x over previous
//
#include <hip/hip_runtime.h>

// SoftPattern: score = sum_{t=4}^{T-1} prod_{p=0}^{4} sigmoid(e_{doc[t-4+p]} . W[:,p] + b[p])
// W = diags[1]; only pattern positions 0..4 contribute.
//
// Structure = R5 (3 kernels; atomic-ticket fusion measured +8-12us in R4/R6 -> rejected).
// K1 is latency-bound on L3-resident emb reads and scales with resident waves/CU
// (R1: 3.1 w/CU -> 48us; R3/R5: 9.2 w/CU -> ~15us; R7: 4.6 w/CU -> regression).
// This round: GROUPS 6->12 (DCHUNK 25), block 384->768 -> 18.3 waves/CU, same traffic.
//
// K1: fused projection+combine+sigmoid -> sig[v][8]
//     block=768: 12 d-groups (25 rows) x 64 lanes; VBLK=128 (float2, 512B segs); grid=391.
// K2: windowed 5-term products, LDS-staged token rows, 1024-thread blocks (as R5)
// K3: final deterministic reduction (as R5)

#define WORD_DIM 300
#define VOCAB    50000
#define PLEN     6
#define DOC_LEN  500000

#define GROUPS   12
#define DCHUNK   25                    // WORD_DIM / GROUPS
#define K1_BLOCK (GROUPS * 64)         // 768
#define VBLK     128                   // 64 lanes x float2

// ------------- K1: sig[v][p] = sigmoid(sum_d E[d][v]*W[d][p] + b[p]) -------------
__global__ __launch_bounds__(K1_BLOCK, 6) void proj_sig_fused(
    const float* __restrict__ emb,     // (WORD_DIM, VOCAB)
    const float* __restrict__ diags,   // (3, WORD_DIM, PLEN)
    const float* __restrict__ bias,    // (3, PLEN)
    float* __restrict__ sig)           // (VOCAB, 8) rows, cols 0..4 valid
{
    __shared__ float wl[WORD_DIM * 8];                   // 9.6 KB, 32B rows -> b128 merge
    __shared__ float part[GROUPS - 1][64][11];           // 30.9 KB, odd stride: conflict-free
    const int tid = threadIdx.x;
    for (int i = tid; i < WORD_DIM * 5; i += K1_BLOCK) {
        int d = i / 5, p = i % 5;
        wl[d * 8 + p] = diags[WORD_DIM * PLEN + d * PLEN + p];   // diags[1][d][p]
    }
    __syncthreads();

    const int g   = tid >> 6;          // d-group == wave index
    const int u   = tid & 63;          // lane
    const int v2  = blockIdx.x * VBLK + u * 2;
    const bool act = (v2 < VOCAB);     // last block: 40 active lanes
    const int d0  = g * DCHUNK;

    float a[10] = {0.f, 0.f, 0.f, 0.f, 0.f, 0.f, 0.f, 0.f, 0.f, 0.f};
    if (act) {
        const float* __restrict__ col = emb + (size_t)d0 * VOCAB + v2;
        #pragma unroll 5
        for (int dd = 0; dd < DCHUNK; ++dd) {
            float2 x = *reinterpret_cast<const float2*>(&col[(size_t)dd * VOCAB]);
            const float* w = &wl[(d0 + dd) * 8];         // 32B-aligned -> b128+b32 merge
            a[0] += x.x * w[0]; a[1] += x.x * w[1]; a[2] += x.x * w[2];
            a[3] += x.x * w[3]; a[4] += x.x * w[4];
            a[5] += x.y * w[0]; a[6] += x.y * w[1]; a[7] += x.y * w[2];
            a[8] += x.y * w[3]; a[9] += x.y * w[4];
        }
    }
    if (g > 0 && act) {
        #pragma unroll
        for (int k = 0; k < 10; ++k) part[g - 1][u][k] = a[k];
    }
    __syncthreads();
    if (g == 0 && act) {
        #pragma unroll
        for (int k = 0; k < 10; ++k) {
            float s = a[k];
            #pragma unroll
            for (int q = 0; q < GROUPS - 1; ++q) s += part[q][u][k];
            a[k] = s;
        }
        float* r0 = &sig[(size_t)v2 * 8];
        float* r1 = &sig[(size_t)(v2 + 1) * 8];
        #pragma unroll
        for (int p = 0; p < 5; ++p) {
            float b = bias[PLEN + p];                    // bias[1][p]
            r0[p] = 1.f / (1.f + __expf(-(a[p]     + b)));
            r1[p] = 1.f / (1.f + __expf(-(a[5 + p] + b)));
        }
    }
}

// ------------- K2: windowed products, LDS-staged rows -------------
#define K2_BLOCK 1024
#define K2_TOK   (K2_BLOCK + 4)

__global__ __launch_bounds__(K2_BLOCK) void score_kernel(
    const int* __restrict__ doc,
    const float* __restrict__ sig,     // (VOCAB, 8)
    float* __restrict__ partials)
{
    __shared__ float srow[5][K2_TOK];  // plane-per-position: conflict-free stride-1
    const int tid  = threadIdx.x;
    const int base = blockIdx.x * K2_BLOCK + 4;          // first window end t
    for (int i = tid; i < K2_TOK; i += K2_BLOCK) {
        int tok_t = base - 4 + i;
        if (tok_t < DOC_LEN) {
            const float* row = &sig[(size_t)doc[tok_t] * 8];
            float4 r4 = *reinterpret_cast<const float4*>(row);
            srow[0][i] = r4.x; srow[1][i] = r4.y; srow[2][i] = r4.z; srow[3][i] = r4.w;
            srow[4][i] = row[4];
        }
    }
    __syncthreads();

    const int t = base + tid;
    float prod = 0.f;
    if (t < DOC_LEN) {
        prod = srow[0][tid] * srow[1][tid + 1] * srow[2][tid + 2]
             * srow[3][tid + 3] * srow[4][tid + 4];
    }
    #pragma unroll
    for (int off = 32; off > 0; off >>= 1)
        prod += __shfl_down(prod, off, 64);
    __shared__ float wsum[K2_BLOCK / 64];
    const int lane = tid & 63;
    const int wid  = tid >> 6;
    if (lane == 0) wsum[wid] = prod;
    __syncthreads();
    if (tid == 0) {
        float s = 0.f;
        #pragma unroll
        for (int w = 0; w < K2_BLOCK / 64; ++w) s += wsum[w];
        partials[blockIdx.x] = s;
    }
}

// ------------- K3: final reduction -------------
__global__ __launch_bounds__(512) void reduce_kernel(
    const float* __restrict__ partials, int n, float* __restrict__ out)
{
    float s = 0.f;
    for (int i = threadIdx.x; i < n; i += 512) s += partials[i];
    #pragma unroll
    for (int off = 32; off > 0; off >>= 1)
        s += __shfl_down(s, off, 64);
    __shared__ float wsum[8];
    const int lane = threadIdx.x & 63;
    const int wid  = threadIdx.x >> 6;
    if (lane == 0) wsum[wid] = s;
    __syncthreads();
    if (threadIdx.x == 0) {
        float t = 0.f;
        #pragma unroll
        for (int w = 0; w < 8; ++w) t += wsum[w];
        out[0] = t;
    }
}

extern "C" void kernel_launch(void* const* d_in, const int* in_sizes, int n_in,
                              void* d_out, int out_size, void* d_ws, size_t ws_size,
                              hipStream_t stream) {
    const float* emb   = (const float*)d_in[0];   // (300, 50000)
    const float* diags = (const float*)d_in[1];   // (3, 300, 6)
    const float* bias  = (const float*)d_in[2];   // (3, 6)
    const int*   doc   = (const int*)d_in[3];     // (500000,)
    float* out = (float*)d_out;

    float* ws = (float*)d_ws;
    float* sig   = ws;                            // VOCAB*8 floats = 1.6 MB
    float* bpart = sig + (size_t)VOCAB * 8;       // block partials

    const int blocks1 = (VOCAB + VBLK - 1) / VBLK;                   // 391
    const int nwin    = DOC_LEN - 4;                                 // 499996
    const int blocks2 = (nwin + K2_BLOCK - 1) / K2_BLOCK;            // 489

    proj_sig_fused<<<blocks1, K1_BLOCK, 0, stream>>>(emb, diags, bias, sig);
    score_kernel<<<blocks2, K2_BLOCK, 0, stream>>>(doc, sig, bpart);
    reduce_kernel<<<1, 512, 0, stream>>>(bpart, blocks2, out);
}